// Round 12
// baseline (85.257 us; speedup 1.0000x reference)
//
#include <hip/hip_runtime.h>

// FeedForwardQuantum: out = relu(cos(x+theta) @ W1 + b1) @ W2 + b2
// x: [B,S,E=8] fp32, W1: [8,32], W2: [32,8]. 524288 tokens = 32768 tiles of 16.
//
// R12 = R11 with the nontemporal-builtin type fix: clang requires raw
// ext-vector pointers, not HIP_vector_type<float,4>*. All x loads / out
// stores go through fv4 (float ext_vector_type(4)).
//  - grid 4096 blocks: 16384 waves (16/SIMD), 2 tiles/wave (R10 was 4/SIMD
//    x 8 serial iters -> exposed latency at iter boundaries).
//  - nontemporal x loads + out stores (read-once/write-once streams).
// Per 16-token tile: 2 MFMA (H^T = W1^T.Q^T + b1), relu, 8 ds_bpermute
// layout transform (target-side lo/hi select), 1 MFMA (O^T = W2^T.H^T + b2).

#define TPB 256

typedef _Float16 h8 __attribute__((ext_vector_type(8)));
typedef __fp16   fp16x2 __attribute__((ext_vector_type(2)));
typedef float    f4 __attribute__((ext_vector_type(4)));
typedef float    fv4 __attribute__((ext_vector_type(4)));

union H2I { fp16x2 h; int i; };
union I4H8 { int i[4]; h8 h; };

__device__ __forceinline__ int pack_f16(float a, float b) {
    H2I u;
    u.h = __builtin_amdgcn_cvt_pkrtz(a, b);   // low=a, high=b
    return u.i;
}

__global__ __launch_bounds__(TPB) void ffq_kernel(
    const fv4* __restrict__ xv,         // x as fv4 pairs: token g -> xv[2g], xv[2g+1]
    const float* __restrict__ theta,    // [8]
    const float* __restrict__ w1,       // [8][32] row-major
    const float* __restrict__ b1,       // [32]
    const float* __restrict__ w2,       // [32][8] row-major
    const float* __restrict__ b2,       // [8]
    fv4*       __restrict__ outv,       // out as fv4 pairs
    int ntile, int nwaves)
{
    const int tid  = threadIdx.x;
    const int lane = tid & 63;
    const int widx = tid >> 6;
    const int quad = lane >> 4;
    const int m16  = lane & 15;

    // ---- one-time setup: weight fragments in registers ----
    h8 a1lo, a1hi, a2;
#pragma unroll
    for (int j = 0; j < 8; ++j) { a1lo[j] = (_Float16)0; a1hi[j] = (_Float16)0; a2[j] = (_Float16)0; }

    if (quad == 0) {
        // A1[m=f][k=e]: real k only 0..7 (quad 0). f = m16 (lo) / m16+16 (hi).
#pragma unroll
        for (int j = 0; j < 8; ++j) {
            a1lo[j] = (_Float16)w1[j * 32 + m16];
            a1hi[j] = (_Float16)w1[j * 32 + 16 + m16];
        }
    }
    if (m16 < 8) {
        // A2[m=e][k=f]: e = m16 (real if <8), f = quad*8+j.
#pragma unroll
        for (int j = 0; j < 8; ++j)
            a2[j] = (_Float16)w2[(quad * 8 + j) * 8 + m16];
    }

    // Bias C-inits. D row m = quad*4 + reg.
    f4 c1lo0, c1hi0, c20;
#pragma unroll
    for (int r = 0; r < 4; ++r) {
        c1lo0[r] = b1[quad * 4 + r];
        c1hi0[r] = b1[16 + quad * 4 + r];
        c20[r]   = (quad < 2) ? b2[quad * 4 + r] : 0.0f;
    }

    float th[8];
#pragma unroll
    for (int e = 0; e < 8; ++e) th[e] = theta[e];

    // bpermute byte-addresses: src lane = qs*16 + t, qs = (2q + (p>>1)) & 3.
    const int addr0 = (((2 * quad) & 3) * 16 + m16) * 4;      // p = 0,1
    const int addr1 = (((2 * quad + 1) & 3) * 16 + m16) * 4;  // p = 2,3

    const int wid = blockIdx.x * (TPB / 64) + widx;

    // distance-1 x prefetch (nontemporal: read-once stream)
    fv4 curA = (fv4)(0.0f);
    fv4 curC = (fv4)(0.0f);
    if (wid < ntile && lane < 16) {
        const int tok = wid * 16 + lane;
        curA = __builtin_nontemporal_load(&xv[2 * tok]);
        curC = __builtin_nontemporal_load(&xv[2 * tok + 1]);
    }

    for (int tile = wid; tile < ntile; tile += nwaves) {
        fv4 nA = curA, nC = curC;
        const int nxt = tile + nwaves;
        if (nxt < ntile && lane < 16) {
            const int tok = nxt * 16 + lane;
            nA = __builtin_nontemporal_load(&xv[2 * tok]);
            nC = __builtin_nontemporal_load(&xv[2 * tok + 1]);
        }

        // ---- B1 = Q^T fragment: lanes 0-15 hold token m16's q[0..7]; k>=8 zero ----
        h8 bq;
#pragma unroll
        for (int j = 0; j < 8; ++j) bq[j] = (_Float16)0;
        if (lane < 16) {
            bq[0] = (_Float16)__cosf(curA.x + th[0]);
            bq[1] = (_Float16)__cosf(curA.y + th[1]);
            bq[2] = (_Float16)__cosf(curA.z + th[2]);
            bq[3] = (_Float16)__cosf(curA.w + th[3]);
            bq[4] = (_Float16)__cosf(curC.x + th[4]);
            bq[5] = (_Float16)__cosf(curC.y + th[5]);
            bq[6] = (_Float16)__cosf(curC.z + th[6]);
            bq[7] = (_Float16)__cosf(curC.w + th[7]);
        }

        // ---- H^T = W1^T . Q^T + b1 ----
        f4 c1lo = __builtin_amdgcn_mfma_f32_16x16x32_f16(a1lo, bq, c1lo0, 0, 0, 0);
        f4 c1hi = __builtin_amdgcn_mfma_f32_16x16x32_f16(a1hi, bq, c1hi0, 0, 0, 0);

        // relu
#pragma unroll
        for (int r = 0; r < 4; ++r) {
            c1lo[r] = fmaxf(c1lo[r], 0.0f);
            c1hi[r] = fmaxf(c1hi[r], 0.0f);
        }

        // ---- C-layout -> B-operand layout (target-side lo/hi select) ----
        const int lo01 = pack_f16(c1lo[0], c1lo[1]);
        const int lo23 = pack_f16(c1lo[2], c1lo[3]);
        const int hi01 = pack_f16(c1hi[0], c1hi[1]);
        const int hi23 = pack_f16(c1hi[2], c1hi[3]);

        const int tL0 = __builtin_amdgcn_ds_bpermute(addr0, lo01);
        const int tL1 = __builtin_amdgcn_ds_bpermute(addr0, lo23);
        const int tL2 = __builtin_amdgcn_ds_bpermute(addr1, lo01);
        const int tL3 = __builtin_amdgcn_ds_bpermute(addr1, lo23);
        const int tH0 = __builtin_amdgcn_ds_bpermute(addr0, hi01);
        const int tH1 = __builtin_amdgcn_ds_bpermute(addr0, hi23);
        const int tH2 = __builtin_amdgcn_ds_bpermute(addr1, hi01);
        const int tH3 = __builtin_amdgcn_ds_bpermute(addr1, hi23);

        I4H8 bh;
        bh.i[0] = (quad < 2) ? tL0 : tH0;   // p=0: f = 8q+0,1
        bh.i[1] = (quad < 2) ? tL1 : tH1;   // p=1: f = 8q+2,3
        bh.i[2] = (quad < 2) ? tL2 : tH2;   // p=2: f = 8q+4,5
        bh.i[3] = (quad < 2) ? tL3 : tH3;   // p=3: f = 8q+6,7

        // ---- O^T = W2^T . H^T + b2 ----
        f4 o = __builtin_amdgcn_mfma_f32_16x16x32_f16(a2, bh.h, c20, 0, 0, 0);

        // D row m = quad*4+r = e. Lane (q<2, t) stores out[t][4q..4q+3].
        if (quad < 2) {
            const int tok = tile * 16 + m16;
            fv4 ov;
            ov.x = o[0]; ov.y = o[1]; ov.z = o[2]; ov.w = o[3];
            __builtin_nontemporal_store(ov, &outv[2 * tok + quad]);
        }

        curA = nA; curC = nC;
    }
}

extern "C" void kernel_launch(void* const* d_in, const int* in_sizes, int n_in,
                              void* d_out, int out_size, void* d_ws, size_t ws_size,
                              hipStream_t stream) {
    const float* x     = (const float*)d_in[0];
    const float* theta = (const float*)d_in[1];
    const float* w1    = (const float*)d_in[2];
    const float* b1    = (const float*)d_in[3];
    const float* w2    = (const float*)d_in[4];
    const float* b2    = (const float*)d_in[5];
    float* out = (float*)d_out;

    const int ntok  = in_sizes[0] / 8;     // 524288
    const int ntile = ntok / 16;           // 32768 (exact)
    const int grid  = 4096;                // 16384 waves -> 2 tiles/wave, 16 waves/SIMD
    const int nwaves = grid * (TPB / 64);

    ffq_kernel<<<grid, TPB, 0, stream>>>(
        (const fv4*)x, theta, w1, b1, w2, b2, (fv4*)out, ntile, nwaves);
}

// Round 13
// 81.119 us; speedup vs baseline: 1.0510x; 1.0510x over previous
//
#include <hip/hip_runtime.h>

// FeedForwardQuantum: out = relu(cos(x+theta) @ W1 + b1) @ W2 + b2
// x: [B,S,E=8] fp32, W1: [8,32], W2: [32,8]. 524288 tokens = 32768 tiles of 16.
//
// R13 = R10 (best: 81.27) with ONE change: grid 1024 -> 2048 (8192 waves,
// 4 tiles/wave). Reverts R12's nontemporal accesses (regression: nt skips
// LLC allocation; x is LLC-hot from the harness restore, nt turned hits
// into HBM round-trips). More resident waves (toward the ~5-6/SIMD VGPR
// cap) cover the ~900cyc load latency that distance-1 prefetch leaves
// marginally exposed at 4 waves/SIMD.
//
// Design: weights ONCE per wave in MFMA A-fragments (12 VGPRs). Per
// 16-token tile: 2 MFMA (H^T = W1^T.Q^T + b1), relu, 8 ds_bpermute C->B
// transform (target-side lo/hi select), 1 MFMA (O^T = W2^T.H^T + b2).
// Layouts (guide-verified): A[m=lane&15][k=quad*8+j],
// D[row=quad*4+reg][col=lane&15], B[k=quad*8+j][n=lane&15].

#define TPB 256

typedef _Float16 h8 __attribute__((ext_vector_type(8)));
typedef __fp16   fp16x2 __attribute__((ext_vector_type(2)));
typedef float    f4 __attribute__((ext_vector_type(4)));

union H2I { fp16x2 h; int i; };
union I4H8 { int i[4]; h8 h; };

__device__ __forceinline__ int pack_f16(float a, float b) {
    H2I u;
    u.h = __builtin_amdgcn_cvt_pkrtz(a, b);   // low=a, high=b
    return u.i;
}

__global__ __launch_bounds__(TPB) void ffq_kernel(
    const float4* __restrict__ xv,      // x as float4 pairs: token g -> xv[2g], xv[2g+1]
    const float*  __restrict__ theta,   // [8]
    const float*  __restrict__ w1,      // [8][32] row-major
    const float*  __restrict__ b1,      // [32]
    const float*  __restrict__ w2,      // [32][8] row-major
    const float*  __restrict__ b2,      // [8]
    float4*       __restrict__ outv,    // out as float4 pairs
    int ntile, int nwaves)
{
    const int tid  = threadIdx.x;
    const int lane = tid & 63;
    const int widx = tid >> 6;
    const int quad = lane >> 4;
    const int m16  = lane & 15;

    // ---- one-time setup: weight fragments in registers ----
    h8 a1lo, a1hi, a2;
#pragma unroll
    for (int j = 0; j < 8; ++j) { a1lo[j] = (_Float16)0; a1hi[j] = (_Float16)0; a2[j] = (_Float16)0; }

    if (quad == 0) {
        // A1[m=f][k=e]: real k only 0..7 (quad 0). f = m16 (lo) / m16+16 (hi).
#pragma unroll
        for (int j = 0; j < 8; ++j) {
            a1lo[j] = (_Float16)w1[j * 32 + m16];
            a1hi[j] = (_Float16)w1[j * 32 + 16 + m16];
        }
    }
    if (m16 < 8) {
        // A2[m=e][k=f]: e = m16 (real if <8), f = quad*8+j.
#pragma unroll
        for (int j = 0; j < 8; ++j)
            a2[j] = (_Float16)w2[(quad * 8 + j) * 8 + m16];
    }

    // Bias C-inits. D row m = quad*4 + reg.
    f4 c1lo0, c1hi0, c20;
#pragma unroll
    for (int r = 0; r < 4; ++r) {
        c1lo0[r] = b1[quad * 4 + r];
        c1hi0[r] = b1[16 + quad * 4 + r];
        c20[r]   = (quad < 2) ? b2[quad * 4 + r] : 0.0f;
    }

    float th[8];
#pragma unroll
    for (int e = 0; e < 8; ++e) th[e] = theta[e];

    // bpermute byte-addresses: src lane = qs*16 + t, qs = (2q + (p>>1)) & 3.
    const int addr0 = (((2 * quad) & 3) * 16 + m16) * 4;      // p = 0,1
    const int addr1 = (((2 * quad + 1) & 3) * 16 + m16) * 4;  // p = 2,3

    const int wid = blockIdx.x * (TPB / 64) + widx;

    // distance-1 x prefetch
    float4 curA = make_float4(0.f, 0.f, 0.f, 0.f);
    float4 curC = curA;
    if (wid < ntile && lane < 16) {
        const int tok = wid * 16 + lane;
        curA = xv[2 * tok];
        curC = xv[2 * tok + 1];
    }

    for (int tile = wid; tile < ntile; tile += nwaves) {
        float4 nA = curA, nC = curC;
        const int nxt = tile + nwaves;
        if (nxt < ntile && lane < 16) {
            const int tok = nxt * 16 + lane;
            nA = xv[2 * tok];
            nC = xv[2 * tok + 1];
        }

        // ---- B1 = Q^T fragment: lanes 0-15 hold token m16's q[0..7]; k>=8 zero ----
        h8 bq;
#pragma unroll
        for (int j = 0; j < 8; ++j) bq[j] = (_Float16)0;
        if (lane < 16) {
            bq[0] = (_Float16)__cosf(curA.x + th[0]);
            bq[1] = (_Float16)__cosf(curA.y + th[1]);
            bq[2] = (_Float16)__cosf(curA.z + th[2]);
            bq[3] = (_Float16)__cosf(curA.w + th[3]);
            bq[4] = (_Float16)__cosf(curC.x + th[4]);
            bq[5] = (_Float16)__cosf(curC.y + th[5]);
            bq[6] = (_Float16)__cosf(curC.z + th[6]);
            bq[7] = (_Float16)__cosf(curC.w + th[7]);
        }

        // ---- H^T = W1^T . Q^T + b1 ----
        f4 c1lo = __builtin_amdgcn_mfma_f32_16x16x32_f16(a1lo, bq, c1lo0, 0, 0, 0);
        f4 c1hi = __builtin_amdgcn_mfma_f32_16x16x32_f16(a1hi, bq, c1hi0, 0, 0, 0);

        // relu
#pragma unroll
        for (int r = 0; r < 4; ++r) {
            c1lo[r] = fmaxf(c1lo[r], 0.0f);
            c1hi[r] = fmaxf(c1hi[r], 0.0f);
        }

        // ---- C-layout -> B-operand layout (target-side lo/hi select) ----
        const int lo01 = pack_f16(c1lo[0], c1lo[1]);
        const int lo23 = pack_f16(c1lo[2], c1lo[3]);
        const int hi01 = pack_f16(c1hi[0], c1hi[1]);
        const int hi23 = pack_f16(c1hi[2], c1hi[3]);

        const int tL0 = __builtin_amdgcn_ds_bpermute(addr0, lo01);
        const int tL1 = __builtin_amdgcn_ds_bpermute(addr0, lo23);
        const int tL2 = __builtin_amdgcn_ds_bpermute(addr1, lo01);
        const int tL3 = __builtin_amdgcn_ds_bpermute(addr1, lo23);
        const int tH0 = __builtin_amdgcn_ds_bpermute(addr0, hi01);
        const int tH1 = __builtin_amdgcn_ds_bpermute(addr0, hi23);
        const int tH2 = __builtin_amdgcn_ds_bpermute(addr1, hi01);
        const int tH3 = __builtin_amdgcn_ds_bpermute(addr1, hi23);

        I4H8 bh;
        bh.i[0] = (quad < 2) ? tL0 : tH0;   // p=0: f = 8q+0,1
        bh.i[1] = (quad < 2) ? tL1 : tH1;   // p=1: f = 8q+2,3
        bh.i[2] = (quad < 2) ? tL2 : tH2;   // p=2: f = 8q+4,5
        bh.i[3] = (quad < 2) ? tL3 : tH3;   // p=3: f = 8q+6,7

        // ---- O^T = W2^T . H^T + b2 ----
        f4 o = __builtin_amdgcn_mfma_f32_16x16x32_f16(a2, bh.h, c20, 0, 0, 0);

        // D row m = quad*4+r = e. Lane (q<2, t) stores out[t][4q..4q+3].
        if (quad < 2) {
            const int tok = tile * 16 + m16;
            outv[2 * tok + quad] = make_float4(o[0], o[1], o[2], o[3]);
        }

        curA = nA; curC = nC;
    }
}

extern "C" void kernel_launch(void* const* d_in, const int* in_sizes, int n_in,
                              void* d_out, int out_size, void* d_ws, size_t ws_size,
                              hipStream_t stream) {
    const float* x     = (const float*)d_in[0];
    const float* theta = (const float*)d_in[1];
    const float* w1    = (const float*)d_in[2];
    const float* b1    = (const float*)d_in[3];
    const float* w2    = (const float*)d_in[4];
    const float* b2    = (const float*)d_in[5];
    float* out = (float*)d_out;

    const int ntok  = in_sizes[0] / 8;     // 524288
    const int ntile = ntok / 16;           // 32768 (exact)
    const int grid  = 2048;                // 8192 waves -> 4 tiles/wave
    const int nwaves = grid * (TPB / 64);

    ffq_kernel<<<grid, TPB, 0, stream>>>(
        (const float4*)x, theta, w1, b1, w2, b2, (float4*)out, ntile, nwaves);
}

// Round 14
// 80.830 us; speedup vs baseline: 1.0548x; 1.0036x over previous
//
#include <hip/hip_runtime.h>

// FeedForwardQuantum: out = relu(cos(x+theta) @ W1 + b1) @ W2 + b2
// x: [B,S,E=8] fp32, W1: [8,32], W2: [32,8]. 524288 tokens = 16384 tiles of 32.
//
// R14: 32-token tiles. Layer 1 = ONE mfma_f32_32x32x16_f16 per 32 tokens
// (A = W1^T all 32 f rows, K=16 covers E=8 + pad; B lanes 0-31 = 32 real
// tokens -> 2x lane utilization vs R10's 16/64). Layer 2 = two verified
// 16x16x32 MFMAs (K=32 = F exact). C(32x32)->B(16x16) transform via
// per-wave LDS scratch (bpermute can't: needed source REG index 2q+(p&1)
// is non-uniform across target lanes). Stride-9 int padding -> <=2-way
// bank aliasing (free). No barriers: same-wave DS ordering.
// Layouts (guide-verified): 32x32 C/D row=(r&3)+8*(r>>2)+4*(lane>>5),
// col=lane&31; A 32x32x16: m=lane&31, k=(lane>>5)*8+j; 16x16x32 as R10.

#define TPB 256

typedef _Float16 h8  __attribute__((ext_vector_type(8)));
typedef __fp16   fp16x2 __attribute__((ext_vector_type(2)));
typedef float    f4  __attribute__((ext_vector_type(4)));
typedef float    f16v __attribute__((ext_vector_type(16)));

union H2I { fp16x2 h; int i; };
union I4H8 { int i[4]; h8 h; };

__device__ __forceinline__ int pack_f16(float a, float b) {
    H2I u;
    u.h = __builtin_amdgcn_cvt_pkrtz(a, b);   // low=a, high=b
    return u.i;
}

__global__ __launch_bounds__(TPB) void ffq_kernel(
    const float4* __restrict__ xv,      // x as float4 pairs: token g -> xv[2g], xv[2g+1]
    const float*  __restrict__ theta,   // [8]
    const float*  __restrict__ w1,      // [8][32] row-major
    const float*  __restrict__ b1,      // [32]
    const float*  __restrict__ w2,      // [32][8] row-major
    const float*  __restrict__ b2,      // [8]
    float4*       __restrict__ outv,    // out as float4 pairs
    int ntile, int nwaves)
{
    // per-wave LDS scratch: 64 lanes x 9 ints (stride 9 = bank padding)
    __shared__ int lds[4 * 576];

    const int tid  = threadIdx.x;
    const int lane = tid & 63;
    const int widx = tid >> 6;
    const int half = lane >> 5;       // 32x32 operand half
    const int l31  = lane & 31;
    const int quad = (lane >> 4) & 3; // 16x16 operand quad
    const int m16  = lane & 15;

    // ---- one-time setup ----
    // A1 (32x32x16): A[m=f=l31][k=half*8+j] = W1[k][f] for half 0, pad 0.
    h8 a1;
#pragma unroll
    for (int j = 0; j < 8; ++j)
        a1[j] = (half == 0) ? (_Float16)w1[j * 32 + l31] : (_Float16)0;

    // A2 (16x16x32): A[m=e=m16][k=f=quad*8+j] = W2[f][e]  (R10-verified)
    h8 a2;
#pragma unroll
    for (int j = 0; j < 8; ++j)
        a2[j] = (m16 < 8) ? (_Float16)w2[(quad * 8 + j) * 8 + m16] : (_Float16)0;

    // C1 init (32x32 D layout): row f_r = (r&3) + 8*(r>>2) + 4*half
    f16v c10;
#pragma unroll
    for (int r = 0; r < 16; ++r)
        c10[r] = b1[(r & 3) + 8 * (r >> 2) + 4 * half];

    // C2 init (16x16 D layout): row e = quad*4+r, real quads 0,1
    f4 c20;
#pragma unroll
    for (int r = 0; r < 4; ++r)
        c20[r] = (quad < 2) ? b2[quad * 4 + r] : 0.0f;

    float th[8];
#pragma unroll
    for (int e = 0; e < 8; ++e) th[e] = theta[e];

    const int base_w = widx * 576;
    const int wid = blockIdx.x * (TPB / 64) + widx;

    // distance-1 x prefetch: lanes 0-31 load token tile*32+l31 (1KB/wave, coalesced)
    float4 curA = make_float4(0.f, 0.f, 0.f, 0.f);
    float4 curC = curA;
    if (wid < ntile && half == 0) {
        const int tok = wid * 32 + l31;
        curA = xv[2 * tok];
        curC = xv[2 * tok + 1];
    }

    for (int tile = wid; tile < ntile; tile += nwaves) {
        float4 nA = curA, nC = curC;
        const int nxt = tile + nwaves;
        if (nxt < ntile && half == 0) {
            const int tok = nxt * 32 + l31;
            nA = xv[2 * tok];
            nC = xv[2 * tok + 1];
        }

        // ---- B1: lanes 0-31 hold token l31's q[0..7] at k=j; half 1 zero ----
        h8 bq;
#pragma unroll
        for (int j = 0; j < 8; ++j) bq[j] = (_Float16)0;
        if (half == 0) {
            bq[0] = (_Float16)__cosf(curA.x + th[0]);
            bq[1] = (_Float16)__cosf(curA.y + th[1]);
            bq[2] = (_Float16)__cosf(curA.z + th[2]);
            bq[3] = (_Float16)__cosf(curA.w + th[3]);
            bq[4] = (_Float16)__cosf(curC.x + th[4]);
            bq[5] = (_Float16)__cosf(curC.y + th[5]);
            bq[6] = (_Float16)__cosf(curC.z + th[6]);
            bq[7] = (_Float16)__cosf(curC.w + th[7]);
        }

        // ---- H^T[f][t] (32x32) = W1^T . Q^T + b1 ----
        f16v c1 = __builtin_amdgcn_mfma_f32_32x32x16_f16(a1, bq, c10, 0, 0, 0);

        // relu + pack: pk[i] = f16pair(f = (2i&3)+8*(i>>1)+4*half, f+1) at col t=l31
#pragma unroll
        for (int r = 0; r < 16; ++r) c1[r] = fmaxf(c1[r], 0.0f);
        int pk[8];
#pragma unroll
        for (int i = 0; i < 8; ++i) pk[i] = pack_f16(c1[2 * i], c1[2 * i + 1]);

        // ---- LDS round-trip transform (same-wave, no barrier) ----
#pragma unroll
        for (int i = 0; i < 8; ++i)
            lds[base_w + lane * 9 + i] = pk[i];

        // Target (quad, m16), token group tg, int p needs f-pair (8q+2p, +1):
        // src lane s = 32*(p>>1) + 16*tg + m16, pack index i = 2*quad + (p&1).
#pragma unroll
        for (int tg = 0; tg < 2; ++tg) {
            I4H8 bh;
#pragma unroll
            for (int p = 0; p < 4; ++p)
                bh.i[p] = lds[base_w + (32 * (p >> 1) + 16 * tg + m16) * 9
                              + 2 * quad + (p & 1)];

            // ---- O^T = W2^T . H^T + b2 (16x16x32, K=32=F exact) ----
            f4 o = __builtin_amdgcn_mfma_f32_16x16x32_f16(a2, bh.h, c20, 0, 0, 0);

            // D row e = quad*4+r (quads 0,1 real), col = token 16*tg+m16
            if (quad < 2) {
                const int tok = tile * 32 + 16 * tg + m16;
                outv[2 * tok + quad] = make_float4(o[0], o[1], o[2], o[3]);
            }
        }

        curA = nA; curC = nC;
    }
}

extern "C" void kernel_launch(void* const* d_in, const int* in_sizes, int n_in,
                              void* d_out, int out_size, void* d_ws, size_t ws_size,
                              hipStream_t stream) {
    const float* x     = (const float*)d_in[0];
    const float* theta = (const float*)d_in[1];
    const float* w1    = (const float*)d_in[2];
    const float* b1    = (const float*)d_in[3];
    const float* w2    = (const float*)d_in[4];
    const float* b2    = (const float*)d_in[5];
    float* out = (float*)d_out;

    const int ntok  = in_sizes[0] / 8;     // 524288
    const int ntile = ntok / 32;           // 16384 (exact)
    const int grid  = 1024;                // 4096 waves -> 4 tiles/wave
    const int nwaves = grid * (TPB / 64);

    ffq_kernel<<<grid, TPB, 0, stream>>>(
        (const float4*)x, theta, w1, b1, w2, b2, (float4*)out, ntile, nwaves);
}